// Round 7
// baseline (177.603 us; speedup 1.0000x reference)
//
#include <hip/hip_runtime.h>

#define BATCH 512
#define GRID_N 25
#define NODES 625            // 25*25
#define BN (BATCH * NODES)   // 320000
#define F 66
#define D 64
#define WPB 8                // waves per block (512 threads)
#define TPW 5                // tiles per wave
#define NT 40                // tiles per block (40*16 = 640 >= 625; tail clamped)
#define WAVE_F (16 * F)      // 1056 floats per tile slice (4224 B)
#define TAIL_TS (NODES - 16) // 609: clamped start row of tile 39

// vmcnt ledger (per wave, per tile iteration):
//   loads/tile  = 5   (4 full gload_lds + 1 lane<8 tail)
//   stores/tile = 16  (16 unmergeable hout dword-stores; u/v go to LDS = lgkm)
// queue at wait of tile t: [loads_t(5) | stores_{t-1}(16) | loads_{t+1}(5)]
// in-order retirement: vmcnt(21) <=> loads_t retired, stores stay in flight.

typedef short bf16x8 __attribute__((ext_vector_type(8)));  // 8 bf16 bits (4 VGPRs)
typedef float f32x4  __attribute__((ext_vector_type(4)));

// fp32 -> bf16 bits, round-to-nearest-even
__device__ __forceinline__ short f2bf(float f) {
    union { float f; unsigned u; } c; c.f = f;
    unsigned r = c.u + 0x7fffu + ((c.u >> 16) & 1u);
    return (short)(r >> 16);
}

// async global->LDS, 16 B per active lane; LDS dest = wave-uniform base + lane*16
typedef const __attribute__((address_space(1))) void gas_void;
typedef __attribute__((address_space(3))) void las_void;
__device__ __forceinline__ void gload_lds16(const float* g, float* l) {
    __builtin_amdgcn_global_load_lds((gas_void*)g, (las_void*)l, 16, 0, 0);
}

// ---------------- Fused kernel: one block per batch.
// Phase 1 (fc): h = x@Wfc^T+bfc -> hout (global, NT stores); u,v -> LDS.
// Phase 2 (attn): s[k]=leaky(u[n]+v[neigh]+bat); softmax; wout via LDS (NT stores).
// All global writes NON-TEMPORAL: the 93 MB write stream must not evict x from L3.
__global__ __launch_bounds__(512, 2) void fused(
    const float* __restrict__ x, const float* __restrict__ Wfc,
    const float* __restrict__ bfc, const float* __restrict__ Wat,
    const float* __restrict__ bat,
    float* __restrict__ hout, float* __restrict__ wout)
{
    const int tid  = threadIdx.x;
    const int lane = tid & 63;
    const int wid  = tid >> 6;
    const int l15  = lane & 15;
    const int quad = lane >> 4;
    const int b    = blockIdx.x;

    __shared__ float stage[2][WPB][WAVE_F];   // 67,584 B (reused as wout staging in ph2)
    __shared__ float u_lds[640];              // 2,560 B
    __shared__ float v_lds[640];              // 2,560 B -> total 72,704 B, 2 blocks/CU

    const float* xb = x + (size_t)b * NODES * F;

    // ---- stage tile 0 of this wave (wid*5 <= 35 -> never clamped) ----
    {
        const float* src = xb + (size_t)(wid * TPW * 16) * F;
        float* dst = &stage[0][wid][0];
#pragma unroll
        for (int r = 0; r < 4; ++r)
            gload_lds16(src + r * 256 + lane * 4, dst + r * 256);
        if (lane < 8)
            gload_lds16(src + 1024 + lane * 4, dst + 1024);
    }

    const float bat0 = bat[0];

    // ---- per-wave weight fragments (overlap the staging flight) ----
    // B[k][n=lane&15] = Wfc[n][k]
    bf16x8 bfrag[4][3];
#pragma unroll
    for (int t = 0; t < 4; ++t) {
        const float2* wr = (const float2*)Wfc + (t * 16 + l15) * 33;
#pragma unroll
        for (int c = 0; c < 2; ++c) {
            bf16x8 fr;
#pragma unroll
            for (int j2 = 0; j2 < 4; ++j2) {
                const float2 p = wr[c * 16 + quad * 4 + j2];
                fr[j2 * 2]     = f2bf(p.x);
                fr[j2 * 2 + 1] = f2bf(p.y);
            }
            bfrag[t][c] = fr;
        }
        bf16x8 z = {0, 0, 0, 0, 0, 0, 0, 0};            // K-chunk 2: only k=64,65 live
        if (quad == 0) {
            const float2 p = wr[32];
            z[0] = f2bf(p.x); z[1] = f2bf(p.y);
        }
        bfrag[t][2] = z;
    }
    float bft[4], wa1[4], wa2[4];
#pragma unroll
    for (int t = 0; t < 4; ++t) {
        bft[t] = bfc[t * 16 + l15];
        wa1[t] = Wat[t * 16 + l15];
        wa2[t] = Wat[64 + t * 16 + l15];
    }

    // ================= Phase 1: fc over 5 tiles per wave =================
    for (int t = 0; t < TPW; ++t) {
        const int s = t & 1;

        // prefetch next tile into the other wave-private buffer (before the wait)
        if (t + 1 < TPW) {
            const int tile = wid * TPW + t + 1;
            const int ts   = (tile == NT - 1) ? TAIL_TS : tile * 16;  // clamp tail
            const float* src = xb + (size_t)ts * F;
            float* dst = &stage[s ^ 1][wid][0];
#pragma unroll
            for (int r = 0; r < 4; ++r)
                gload_lds16(src + r * 256 + lane * 4, dst + r * 256);
            if (lane < 8)
                gload_lds16(src + 1024 + lane * 4, dst + 1024);
        }
        // store-blind counted wait: retire ONLY this tile's loads (oldest in queue)
        if (t == 0)
            asm volatile("s_waitcnt vmcnt(5)" ::: "memory");
        else if (t + 1 < TPW)
            asm volatile("s_waitcnt vmcnt(21)" ::: "memory");
        else
            asm volatile("s_waitcnt vmcnt(16)" ::: "memory");
        __builtin_amdgcn_sched_barrier(0);

        const int tile = wid * TPW + t;
        const int ts   = (tile == NT - 1) ? TAIL_TS : tile * 16;   // tail recompute, benign
        const float2* wbase = (const float2*)&stage[s][wid][0];

        // ---- A fragments from wave-private LDS; A[m=l15][k=quad*8+j] ----
        const float2* rp = wbase + l15 * 33 + quad * 4;
        bf16x8 afrag[3];
#pragma unroll
        for (int c = 0; c < 2; ++c) {
            bf16x8 fr;
#pragma unroll
            for (int j2 = 0; j2 < 4; ++j2) {
                const float2 p = rp[c * 16 + j2];        // k = c*32 + quad*8 + 2*j2
                fr[j2 * 2]     = f2bf(p.x);
                fr[j2 * 2 + 1] = f2bf(p.y);
            }
            afrag[c] = fr;
        }
        {
            bf16x8 z = {0, 0, 0, 0, 0, 0, 0, 0};
            if (quad == 0) {
                const float2 p = wbase[l15 * 33 + 32];   // k = 64,65
                z[0] = f2bf(p.x); z[1] = f2bf(p.y);
            }
            afrag[2] = z;
        }

        // ---- MFMA: 4 N-tiles x 3 K-chunks; C/D row=quad*4+reg, col=l15 ----
        f32x4 acc[4] = {{0,0,0,0},{0,0,0,0},{0,0,0,0},{0,0,0,0}};
#pragma unroll
        for (int nt = 0; nt < 4; ++nt)
#pragma unroll
            for (int c = 0; c < 3; ++c)
                acc[nt] = __builtin_amdgcn_mfma_f32_16x16x32_bf16(afrag[c], bfrag[nt][c], acc[nt], 0, 0, 0);

        // ---- epilogue: bias, u/v partials, NON-TEMPORAL h stores ----
        const size_t gn0 = (size_t)b * NODES + ts;
        float pu[4] = {0, 0, 0, 0}, pv[4] = {0, 0, 0, 0};
#pragma unroll
        for (int nt = 0; nt < 4; ++nt) {
#pragma unroll
            for (int r = 0; r < 4; ++r) {
                const float h = acc[nt][r] + bft[nt];
                __builtin_nontemporal_store(h, &hout[(gn0 + quad * 4 + r) * D + nt * 16 + l15]);
                pu[r] = fmaf(h, wa1[nt], pu[r]);
                pv[r] = fmaf(h, wa2[nt], pv[r]);
            }
        }
#pragma unroll
        for (int off = 8; off > 0; off >>= 1) {
#pragma unroll
            for (int r = 0; r < 4; ++r) {
                pu[r] += __shfl_xor(pu[r], off, 64);
                pv[r] += __shfl_xor(pv[r], off, 64);
            }
        }
        if (l15 == 0) {                 // u/v stay in LDS (lgkm, not vmcnt)
#pragma unroll
            for (int r = 0; r < 4; ++r) {
                u_lds[ts + quad * 4 + r] = pu[r];
                v_lds[ts + quad * 4 + r] = pv[r];
            }
        }
    }

    __syncthreads();    // all u/v in LDS; all gloads retired; stage reusable

    // ================= Phase 2: attention softmax (block-local) =================
    float* sw = &stage[0][0][0];        // 5625-float wout staging (fits in 16,896)
#pragma unroll
    for (int rnd = 0; rnd < 2; ++rnd) {
        const int ln = tid + rnd * 512;
        if (ln < NODES) {
            const int row = ln / GRID_N;
            const int col = ln - row * GRID_N;
            const int r0 = row + (row == 0) - (row == GRID_N - 1);
            const int c0 = col + (col == 0) - (col == GRID_N - 1);
            const float u0 = u_lds[ln] + bat0;

            float sv[9];
#pragma unroll
            for (int k = 0; k < 9; ++k) {
                const int nr = r0 + (k / 3) - 1;
                const int nc = c0 + (k % 3) - 1;
                const float tt = u0 + v_lds[nr * GRID_N + nc];
                sv[k] = (tt >= 0.0f) ? tt : 0.01f * tt;
            }
            float m = sv[0];
#pragma unroll
            for (int k = 1; k < 9; ++k) m = fmaxf(m, sv[k]);
            float sum = 0.0f;
#pragma unroll
            for (int k = 0; k < 9; ++k) { sv[k] = __expf(sv[k] - m); sum += sv[k]; }
            const float inv = 1.0f / sum;
#pragma unroll
            for (int k = 0; k < 9; ++k) sw[ln * 9 + k] = sv[k] * inv;
        }
    }
    __syncthreads();

    // coalesced NON-TEMPORAL copy: 5625 dwords
    float* wb = wout + (size_t)b * (NODES * 9);
    for (int i = tid; i < NODES * 9; i += 512)
        __builtin_nontemporal_store(sw[i], &wb[i]);
}

extern "C" void kernel_launch(void* const* d_in, const int* in_sizes, int n_in,
                              void* d_out, int out_size, void* d_ws, size_t ws_size,
                              hipStream_t stream)
{
    const float* x   = (const float*)d_in[0];
    const float* Wfc = (const float*)d_in[1];
    const float* bfc = (const float*)d_in[2];
    const float* Wat = (const float*)d_in[3];
    const float* bat = (const float*)d_in[4];

    float* hout = (float*)d_out;                       // [B, N, 64]
    float* wout = (float*)d_out + (size_t)BN * D;      // [B, N, 9]

    fused<<<BATCH, 512, 0, stream>>>(x, Wfc, bfc, Wat, bat, hout, wout);
}

// Round 8
// 170.768 us; speedup vs baseline: 1.0400x; 1.0400x over previous
//
#include <hip/hip_runtime.h>

#define BATCH 512
#define GRID_N 25
#define NODES 625            // 25*25
#define BN (BATCH * NODES)   // 320000
#define NTILES (BN / 16)     // 20000
#define F 66
#define D 64

typedef short bf16x8 __attribute__((ext_vector_type(8)));  // 8 bf16 bits (4 VGPRs)
typedef float f32x4  __attribute__((ext_vector_type(4)));

// fp32 -> bf16 bits, round-to-nearest-even
__device__ __forceinline__ short f2bf(float f) {
    union { float f; unsigned u; } c; c.f = f;
    unsigned r = c.u + 0x7fffu + ((c.u >> 16) & 1u);
    return (short)(r >> 16);
}

// ---------------- Kernel A: occupancy-first MFMA fc.
// h = x@Wfc^T+bfc -> hout ; u=h.Wat[0:64] ; v=h.Wat[64:128] -> workspace.
// B-fragments live in LDS (identical for all waves) -> no 48-VGPR bfrag;
// x rows load straight to registers. Target: 24 waves/CU (6/EU), 2x all
// previous rounds -- tests the occupancy->effective-BW theory.
__global__ __launch_bounds__(256, 6) void fc_mfma(
    const float* __restrict__ x, const float* __restrict__ Wfc,
    const float* __restrict__ bfc, const float* __restrict__ Wat,
    float* __restrict__ hout, float* __restrict__ u, float* __restrict__ v)
{
    const int tid  = threadIdx.x;
    const int lane = tid & 63;
    const int wid  = tid >> 6;
    const int l15  = lane & 15;
    const int quad = lane >> 4;

    __shared__ bf16x8 Bl[12][64];     // [t*3+c][lane] = per-lane B fragment, 12,288 B

    // ---- cooperative B-fragment build: 768 entries over 256 threads ----
    // entry (t,c,ln): what lane ln needs as B[k][n=t*16+(ln&15)], k-chunk c.
#pragma unroll
    for (int e = tid; e < 768; e += 256) {
        const int ln = e & 63;
        const int tc = e >> 6;            // 0..11
        const int t  = tc / 3, c = tc - 3 * t;
        const int L  = ln & 15, Q = ln >> 4;
        const float2* wr = (const float2*)Wfc + (t * 16 + L) * 33;
        bf16x8 fr = {0, 0, 0, 0, 0, 0, 0, 0};
        if (c < 2) {
#pragma unroll
            for (int j2 = 0; j2 < 4; ++j2) {
                const float2 p = wr[c * 16 + Q * 4 + j2];
                fr[j2 * 2]     = f2bf(p.x);
                fr[j2 * 2 + 1] = f2bf(p.y);
            }
        } else if (Q == 0) {              // K-chunk 2: only k=64,65 live
            const float2 p = wr[32];
            fr[0] = f2bf(p.x); fr[1] = f2bf(p.y);
        }
        Bl[tc][ln] = fr;
    }

    // ---- x row -> registers (issued while B-build runs; 8B/lane float2) ----
    const int tile = blockIdx.x * 4 + wid;            // one 16-node tile per wave
    const int bn0  = tile * 16;
    const float2* rp = (const float2*)x + (size_t)tile * 528 + l15 * 33;
    float2 xb[9];
#pragma unroll
    for (int j2 = 0; j2 < 4; ++j2) {
        xb[j2]     = rp[quad * 4 + j2];               // k 0..31  (chunk 0)
        xb[4 + j2] = rp[16 + quad * 4 + j2];          // k 32..63 (chunk 1)
    }
    xb[8] = rp[32];                                   // k 64,65 (used iff quad==0)

    // ---- epilogue constants ----
    float bft[4], wa1[4], wa2[4];
#pragma unroll
    for (int t = 0; t < 4; ++t) {
        bft[t] = bfc[t * 16 + l15];
        wa1[t] = Wat[t * 16 + l15];
        wa2[t] = Wat[64 + t * 16 + l15];
    }

    // ---- A fragments; A[m=l15][k=quad*8+j] ----
    bf16x8 afrag[3];
#pragma unroll
    for (int c = 0; c < 2; ++c) {
        bf16x8 fr;
#pragma unroll
        for (int j2 = 0; j2 < 4; ++j2) {
            const float2 p = xb[c * 4 + j2];
            fr[j2 * 2]     = f2bf(p.x);
            fr[j2 * 2 + 1] = f2bf(p.y);
        }
        afrag[c] = fr;
    }
    {
        bf16x8 z = {0, 0, 0, 0, 0, 0, 0, 0};
        if (quad == 0) { z[0] = f2bf(xb[8].x); z[1] = f2bf(xb[8].y); }
        afrag[2] = z;
    }

    __syncthreads();    // B-fragments visible

    // ---- MFMA: per K-chunk, stream 4 B-frags from LDS (lane-indexed, no conflict).
    // sched_barrier pins per-chunk grouping so only 16 B-regs are live at once.
    f32x4 acc[4] = {{0,0,0,0},{0,0,0,0},{0,0,0,0},{0,0,0,0}};
#pragma unroll
    for (int c = 0; c < 3; ++c) {
        const bf16x8 b0 = Bl[c][lane];
        const bf16x8 b1 = Bl[3 + c][lane];
        const bf16x8 b2 = Bl[6 + c][lane];
        const bf16x8 b3 = Bl[9 + c][lane];
        acc[0] = __builtin_amdgcn_mfma_f32_16x16x32_bf16(afrag[c], b0, acc[0], 0, 0, 0);
        acc[1] = __builtin_amdgcn_mfma_f32_16x16x32_bf16(afrag[c], b1, acc[1], 0, 0, 0);
        acc[2] = __builtin_amdgcn_mfma_f32_16x16x32_bf16(afrag[c], b2, acc[2], 0, 0, 0);
        acc[3] = __builtin_amdgcn_mfma_f32_16x16x32_bf16(afrag[c], b3, acc[3], 0, 0, 0);
        __builtin_amdgcn_sched_barrier(0);
    }

    // ---- epilogue: bias, u/v partials, direct h stores (4 full 64B lines/instr) ----
    float pu[4] = {0, 0, 0, 0}, pv[4] = {0, 0, 0, 0};
#pragma unroll
    for (int nt = 0; nt < 4; ++nt) {
#pragma unroll
        for (int r = 0; r < 4; ++r) {
            const float h = acc[nt][r] + bft[nt];
            hout[(size_t)(bn0 + quad * 4 + r) * D + nt * 16 + l15] = h;
            pu[r] = fmaf(h, wa1[nt], pu[r]);
            pv[r] = fmaf(h, wa2[nt], pv[r]);
        }
    }
#pragma unroll
    for (int off = 8; off > 0; off >>= 1) {
#pragma unroll
        for (int r = 0; r < 4; ++r) {
            pu[r] += __shfl_xor(pu[r], off, 64);
            pv[r] += __shfl_xor(pv[r], off, 64);
        }
    }
    if (l15 == 0) {     // one float4 store each
        *(float4*)(u + bn0 + quad * 4) = make_float4(pu[0], pu[1], pu[2], pu[3]);
        *(float4*)(v + bn0 + quad * 4) = make_float4(pv[0], pv[1], pv[2], pv[3]);
    }
}

// ---------------- Kernel B: s[k] = leaky(u[n] + v[neigh(n,k)] + b_at); softmax over k
// wave-cooperative coalesced output via wave-private LDS
__global__ __launch_bounds__(256) void attn_kernel(
    const float* __restrict__ u, const float* __restrict__ v,
    const float* __restrict__ bat, float* __restrict__ wout)
{
    __shared__ float sw[256 * 9];
    const int tid  = threadIdx.x;
    const int lane = tid & 63;
    const int wid  = tid >> 6;
    const int bn   = blockIdx.x * 256 + tid;        // BN = 1250 * 256 exactly

    const int b   = bn / NODES;
    const int n   = bn - b * NODES;
    const int row = n / GRID_N;
    const int col = n - row * GRID_N;
    // reference's edge clamp: shift whole 3x3 window inward at the borders
    const int r0 = row + (row == 0) - (row == GRID_N - 1);
    const int c0 = col + (col == 0) - (col == GRID_N - 1);

    const float* vb = v + b * NODES;
    const float u0 = u[bn] + bat[0];

    float s[9];
#pragma unroll
    for (int k = 0; k < 9; ++k) {
        const int nr = r0 + (k / 3) - 1;
        const int nc = c0 + (k % 3) - 1;
        const float t = u0 + vb[nr * GRID_N + nc];
        s[k] = (t >= 0.0f) ? t : 0.01f * t;
    }
    float m = s[0];
#pragma unroll
    for (int k = 1; k < 9; ++k) m = fmaxf(m, s[k]);
    float sum = 0.0f;
#pragma unroll
    for (int k = 0; k < 9; ++k) { s[k] = __expf(s[k] - m); sum += s[k]; }
    const float inv = 1.0f / sum;

    float* ws = sw + wid * 576;                     // wave-private 2304 B
#pragma unroll
    for (int k = 0; k < 9; ++k) ws[lane * 9 + k] = s[k] * inv;

    // 576 floats = 144 float4 per wave, fully coalesced
    float4* dst = (float4*)(wout + (size_t)(blockIdx.x * 256 + wid * 64) * 9);
    const float4* src = (const float4*)ws;
    dst[lane]      = src[lane];
    dst[64 + lane] = src[64 + lane];
    if (lane < 16) dst[128 + lane] = src[128 + lane];
}

extern "C" void kernel_launch(void* const* d_in, const int* in_sizes, int n_in,
                              void* d_out, int out_size, void* d_ws, size_t ws_size,
                              hipStream_t stream)
{
    const float* x   = (const float*)d_in[0];
    const float* Wfc = (const float*)d_in[1];
    const float* bfc = (const float*)d_in[2];
    const float* Wat = (const float*)d_in[3];
    const float* bat = (const float*)d_in[4];

    float* hout = (float*)d_out;                       // [B, N, 64]
    float* wout = (float*)d_out + (size_t)BN * D;      // [B, N, 9]
    float* u = (float*)d_ws;                           // [B*N]
    float* v = u + BN;                                 // [B*N]

    fc_mfma<<<NTILES / 4, 256, 0, stream>>>(x, Wfc, bfc, Wat, hout, u, v);
    attn_kernel<<<BN / 256, 256, 0, stream>>>(u, v, bat, wout);
}

// Round 10
// 169.770 us; speedup vs baseline: 1.0461x; 1.0059x over previous
//
#include <hip/hip_runtime.h>

#define BATCH 512
#define GRID_N 25
#define NODES 625            // 25*25
#define BN (BATCH * NODES)   // 320000
#define NTILES (BN / 16)     // 20000
#define F 66
#define D 64

typedef short bf16x8 __attribute__((ext_vector_type(8)));  // 8 bf16 bits (4 VGPRs)
typedef float f32x4  __attribute__((ext_vector_type(4)));

// fp32 -> bf16 bits, round-to-nearest-even
__device__ __forceinline__ short f2bf(float f) {
    union { float f; unsigned u; } c; c.f = f;
    unsigned r = c.u + 0x7fffu + ((c.u >> 16) & 1u);
    return (short)(r >> 16);
}

// async global->LDS, 16 B per active lane; LDS dest = wave-uniform base + lane*16
typedef const __attribute__((address_space(1))) void gas_void;
typedef __attribute__((address_space(3))) void las_void;
__device__ __forceinline__ void gload_lds16(const float* g, float* l) {
    __builtin_amdgcn_global_load_lds((gas_void*)g, (las_void*)l, 16, 0, 0);
}

// ---------------- Setup: pack the 12x64 MFMA B-fragments once per iteration.
// pack[tc*64+ln] = what lane ln needs as B[k][n=t*16+(ln&15)], K-chunk c (tc=t*3+c).
// Lives in the last 12 KB of wout (fully overwritten by attn afterward).
__global__ __launch_bounds__(256) void pack_b(
    const float* __restrict__ Wfc, bf16x8* __restrict__ pack)
{
    const int e = blockIdx.x * 256 + threadIdx.x;     // 0..767
    if (e >= 768) return;
    const int ln = e & 63;
    const int tc = e >> 6;            // 0..11
    const int t  = tc / 3, c = tc - 3 * t;
    const int L  = ln & 15, Q = ln >> 4;
    const float2* wr = (const float2*)Wfc + (t * 16 + L) * 33;
    bf16x8 fr = {0, 0, 0, 0, 0, 0, 0, 0};
    if (c < 2) {
#pragma unroll
        for (int j2 = 0; j2 < 4; ++j2) {
            const float2 p = wr[c * 16 + Q * 4 + j2];
            fr[j2 * 2]     = f2bf(p.x);
            fr[j2 * 2 + 1] = f2bf(p.y);
        }
    } else if (Q == 0) {              // K-chunk 2: only k=64,65 live
        const float2 p = wr[32];
        fr[0] = f2bf(p.x); fr[1] = f2bf(p.y);
    }
    pack[e] = fr;
}

// ---------------- Kernel A: occupancy-first MFMA fc, prepacked B.
// h = x@Wfc^T+bfc -> hout ; u=h.Wat[0:64] ; v=h.Wat[64:128] -> workspace.
// B-fragments staged from the prepacked global buffer via 3 coalesced
// global_load_lds rounds -- no per-block build, minimal pre-barrier chain.
__global__ __launch_bounds__(256, 6) void fc_mfma(
    const float* __restrict__ x, const float* __restrict__ packf,
    const float* __restrict__ bfc, const float* __restrict__ Wat,
    float* __restrict__ hout, float* __restrict__ u, float* __restrict__ v)
{
    const int tid  = threadIdx.x;
    const int lane = tid & 63;
    const int wid  = tid >> 6;
    const int l15  = lane & 15;
    const int quad = lane >> 4;

    __shared__ bf16x8 Bl[12][64];     // 12,288 B

    // ---- stage prepacked B: 3 coalesced rounds, 4 KB each ----
    {
        float* ldsb = (float*)&Bl[0][0];
#pragma unroll
        for (int r = 0; r < 3; ++r)
            gload_lds16(packf + (r * 256 + tid) * 4, ldsb + r * 1024 + wid * 256);
    }

    // ---- x row -> registers (overlaps the B staging flight; 8B/lane float2) ----
    const int tile = blockIdx.x * 4 + wid;            // one 16-node tile per wave
    const int bn0  = tile * 16;
    const float2* rp = (const float2*)x + (size_t)tile * 528 + l15 * 33;
    float2 xb[9];
#pragma unroll
    for (int j2 = 0; j2 < 4; ++j2) {
        xb[j2]     = rp[quad * 4 + j2];               // k 0..31  (chunk 0)
        xb[4 + j2] = rp[16 + quad * 4 + j2];          // k 32..63 (chunk 1)
    }
    xb[8] = rp[32];                                   // k 64,65 (used iff quad==0)

    // ---- epilogue constants ----
    float bft[4], wa1[4], wa2[4];
#pragma unroll
    for (int t = 0; t < 4; ++t) {
        bft[t] = bfc[t * 16 + l15];
        wa1[t] = Wat[t * 16 + l15];
        wa2[t] = Wat[64 + t * 16 + l15];
    }

    // ---- A fragments; A[m=l15][k=quad*8+j] ----
    bf16x8 afrag[3];
#pragma unroll
    for (int c = 0; c < 2; ++c) {
        bf16x8 fr;
#pragma unroll
        for (int j2 = 0; j2 < 4; ++j2) {
            const float2 p = xb[c * 4 + j2];
            fr[j2 * 2]     = f2bf(p.x);
            fr[j2 * 2 + 1] = f2bf(p.y);
        }
        afrag[c] = fr;
    }
    {
        bf16x8 z = {0, 0, 0, 0, 0, 0, 0, 0};
        if (quad == 0) { z[0] = f2bf(xb[8].x); z[1] = f2bf(xb[8].y); }
        afrag[2] = z;
    }

    __syncthreads();    // B-fragments visible (drains the gload_lds)

    // ---- MFMA: per K-chunk, stream 4 B-frags from LDS (lane-indexed) ----
    f32x4 acc[4] = {{0,0,0,0},{0,0,0,0},{0,0,0,0},{0,0,0,0}};
#pragma unroll
    for (int c = 0; c < 3; ++c) {
        const bf16x8 b0 = Bl[c][lane];
        const bf16x8 b1 = Bl[3 + c][lane];
        const bf16x8 b2 = Bl[6 + c][lane];
        const bf16x8 b3 = Bl[9 + c][lane];
        acc[0] = __builtin_amdgcn_mfma_f32_16x16x32_bf16(afrag[c], b0, acc[0], 0, 0, 0);
        acc[1] = __builtin_amdgcn_mfma_f32_16x16x32_bf16(afrag[c], b1, acc[1], 0, 0, 0);
        acc[2] = __builtin_amdgcn_mfma_f32_16x16x32_bf16(afrag[c], b2, acc[2], 0, 0, 0);
        acc[3] = __builtin_amdgcn_mfma_f32_16x16x32_bf16(afrag[c], b3, acc[3], 0, 0, 0);
        __builtin_amdgcn_sched_barrier(0);
    }

    // ---- epilogue: bias, u/v partials, direct h stores (4 full 64B lines/instr) ----
    float pu[4] = {0, 0, 0, 0}, pv[4] = {0, 0, 0, 0};
#pragma unroll
    for (int nt = 0; nt < 4; ++nt) {
#pragma unroll
        for (int r = 0; r < 4; ++r) {
            const float h = acc[nt][r] + bft[nt];
            hout[(size_t)(bn0 + quad * 4 + r) * D + nt * 16 + l15] = h;
            pu[r] = fmaf(h, wa1[nt], pu[r]);
            pv[r] = fmaf(h, wa2[nt], pv[r]);
        }
    }
#pragma unroll
    for (int off = 8; off > 0; off >>= 1) {
#pragma unroll
        for (int r = 0; r < 4; ++r) {
            pu[r] += __shfl_xor(pu[r], off, 64);
            pv[r] += __shfl_xor(pv[r], off, 64);
        }
    }
    if (l15 == 0) {     // one float4 store each
        *(float4*)(u + bn0 + quad * 4) = make_float4(pu[0], pu[1], pu[2], pu[3]);
        *(float4*)(v + bn0 + quad * 4) = make_float4(pv[0], pv[1], pv[2], pv[3]);
    }
}

// ---------------- Kernel B: s[k] = leaky(u[n] + v[neigh(n,k)] + b_at); softmax over k
// wave-cooperative coalesced output via wave-private LDS
__global__ __launch_bounds__(256) void attn_kernel(
    const float* __restrict__ u, const float* __restrict__ v,
    const float* __restrict__ bat, float* __restrict__ wout)
{
    __shared__ float sw[256 * 9];
    const int tid  = threadIdx.x;
    const int lane = tid & 63;
    const int wid  = tid >> 6;
    const int bn   = blockIdx.x * 256 + tid;        // BN = 1250 * 256 exactly

    const int b   = bn / NODES;
    const int n   = bn - b * NODES;
    const int row = n / GRID_N;
    const int col = n - row * GRID_N;
    // reference's edge clamp: shift whole 3x3 window inward at the borders
    const int r0 = row + (row == 0) - (row == GRID_N - 1);
    const int c0 = col + (col == 0) - (col == GRID_N - 1);

    const float* vb = v + b * NODES;
    const float u0 = u[bn] + bat[0];

    float s[9];
#pragma unroll
    for (int k = 0; k < 9; ++k) {
        const int nr = r0 + (k / 3) - 1;
        const int nc = c0 + (k % 3) - 1;
        const float t = u0 + vb[nr * GRID_N + nc];
        s[k] = (t >= 0.0f) ? t : 0.01f * t;
    }
    float m = s[0];
#pragma unroll
    for (int k = 1; k < 9; ++k) m = fmaxf(m, s[k]);
    float sum = 0.0f;
#pragma unroll
    for (int k = 0; k < 9; ++k) { s[k] = __expf(s[k] - m); sum += s[k]; }
    const float inv = 1.0f / sum;

    float* ws = sw + wid * 576;                     // wave-private 2304 B
#pragma unroll
    for (int k = 0; k < 9; ++k) ws[lane * 9 + k] = s[k] * inv;

    // 576 floats = 144 float4 per wave, fully coalesced
    float4* dst = (float4*)(wout + (size_t)(blockIdx.x * 256 + wid * 64) * 9);
    const float4* src = (const float4*)ws;
    dst[lane]      = src[lane];
    dst[64 + lane] = src[64 + lane];
    if (lane < 16) dst[128 + lane] = src[128 + lane];
}

extern "C" void kernel_launch(void* const* d_in, const int* in_sizes, int n_in,
                              void* d_out, int out_size, void* d_ws, size_t ws_size,
                              hipStream_t stream)
{
    const float* x   = (const float*)d_in[0];
    const float* Wfc = (const float*)d_in[1];
    const float* bfc = (const float*)d_in[2];
    const float* Wat = (const float*)d_in[3];
    const float* bat = (const float*)d_in[4];

    float* hout = (float*)d_out;                       // [B, N, 64]
    float* wout = (float*)d_out + (size_t)BN * D;      // [B, N, 9]
    float* u = (float*)d_ws;                           // [B*N]
    float* v = u + BN;                                 // [B*N]

    // prepacked B lives in the LAST 12 KB of wout (3072 floats); attn_kernel
    // rewrites every wout element afterward, so the scratch leaves no trace.
    float* packf = wout + (size_t)BN * 9 - 3072;       // 16B-aligned

    pack_b<<<3, 256, 0, stream>>>(Wfc, (bf16x8*)packf);
    fc_mfma<<<NTILES / 4, 256, 0, stream>>>(x, packf, bfc, Wat, hout, u, v);
    attn_kernel<<<BN / 256, 256, 0, stream>>>(u, v, bat, wout);
}